// Round 1
// baseline (370.689 us; speedup 1.0000x reference)
//
#include <hip/hip_runtime.h>

// Problem constants
#define BATCH     4096
#define N1        128     // n blocks (stage-1 block index, stage-2 K dim)
#define I1        64      // inputs per block 1 (stage-1 K dim)
#define MMID      64      // outputs per block 1 == n blocks 2
#define OOUT      128     // outputs per block 2
#define LDX       8192    // x row length
#define CSP       3.0f

typedef _Float16 half8  __attribute__((ext_vector_type(8)));
typedef _Float16 half4_ __attribute__((ext_vector_type(4)));
typedef float    float4_ __attribute__((ext_vector_type(4)));

// ---------------------------------------------------------------------------
// Kernel 1: softmax prep (unchanged).
//  conn1T[n][m][i] = softmax_i(3*c1[n][i][m])   (fp16, i contiguous)
//  conn2T[m][o][n] = softmax_n(3*c2[m][n][o])   (fp16, n contiguous)
// ---------------------------------------------------------------------------
__global__ __launch_bounds__(256) void prep_kernel(
    const float* __restrict__ c1, const float* __restrict__ c2,
    _Float16* __restrict__ conn1T, _Float16* __restrict__ conn2T) {
  int gid = blockIdx.x * 256 + threadIdx.x;
  if (gid < N1 * MMID) {
    const float* p = c1 + (size_t)(gid >> 6) * (I1 * MMID) + (gid & 63);
    float mx = -1e30f;
    for (int i = 0; i < I1; ++i) mx = fmaxf(mx, p[i * MMID]);
    mx *= CSP;
    float s = 0.f;
    for (int i = 0; i < I1; ++i) s += __expf(p[i * MMID] * CSP - mx);
    float inv = 1.0f / s;
    _Float16* dst = conn1T + (size_t)gid * I1;
    for (int i = 0; i < I1; ++i)
      dst[i] = (_Float16)(__expf(p[i * MMID] * CSP - mx) * inv);
  } else {
    int g = gid - N1 * MMID;
    if (g < MMID * OOUT) {
      const float* p = c2 + (size_t)(g >> 7) * (N1 * OOUT) + (g & 127);
      float mx = -1e30f;
      for (int i = 0; i < N1; ++i) mx = fmaxf(mx, p[i * OOUT]);
      mx *= CSP;
      float s = 0.f;
      for (int i = 0; i < N1; ++i) s += __expf(p[i * OOUT] * CSP - mx);
      float inv = 1.0f / s;
      _Float16* dst = conn2T + (size_t)g * N1;
      for (int i = 0; i < N1; ++i)
        dst[i] = (_Float16)(__expf(p[i * OOUT] * CSP - mx) * inv);
    }
  }
}

// ---------------------------------------------------------------------------
// Kernel 2: FUSED stage1+stage2. Block = (b-tile of 16 rows, m-quarter of 16).
// Phase 1: wave w computes t[b][m0..m0+16][n] for n in [w*32, w*32+32) via
//   MFMA (A = x fp32->fp16, B = conn1T) and writes the 16x16x128 fp16 t-tile
//   to LDS (64 KB), n-position XOR-swizzled by ((b+m)&7)<<4 bytes.
// Phase 2 (one barrier): wave w owns 4 m's; A-frags are swizzled ds_read_b128
//   from LDS, B = conn2T (L2-hot), 32 K=32 MFMAs per m, fp32 stores to out.
// t never touches HBM. Grid id swizzle pins the 4 m-quarter siblings of a
// b-tile to one XCD (ids differ by 8 -> same XCD, co-resident) so the x
// re-reads are L2 hits.  2 blocks/CU (64 KB LDS), 8 waves/CU.
// ---------------------------------------------------------------------------
__global__ __launch_bounds__(256, 2) void fused_kernel(
    const float* __restrict__ x, const _Float16* __restrict__ conn1T,
    const _Float16* __restrict__ conn2T, float* __restrict__ out) {
  __shared__ _Float16 tl[16 * 16 * 128];   // 64 KB: [b][m][n] + XOR swizzle

  const int bid  = blockIdx.x;
  const int bt   = ((bid >> 5) << 3) | (bid & 7);  // b-tile 0..255
  const int q    = (bid >> 3) & 3;                 // m-quarter 0..3
  const int b0   = bt * 16;
  const int m0   = q * 16;
  const int tid  = threadIdx.x;
  const int lane = tid & 63;
  const int wave = tid >> 6;
  const int row  = lane & 15;
  const int quad = lane >> 4;
  const int kk   = quad * 8;

  // ---------------- phase 1: t-tile into LDS ----------------
  const float* xrow = x + (size_t)(b0 + row) * LDX;
  const _Float16* w1m = conn1T + (size_t)(m0 + row) * I1 + kk;

#pragma unroll 2
  for (int g = 0; g < 8; ++g) {
    const int n0 = wave * 32 + g * 4;
    float4_ acc4[4];
#pragma unroll
    for (int nn = 0; nn < 4; ++nn) {
      const int n = n0 + nn;
      const float* ap = xrow + n * I1 + kk;
      float4_ a0lo = *(const float4_*)(ap);
      float4_ a0hi = *(const float4_*)(ap + 4);
      float4_ a1lo = *(const float4_*)(ap + 32);
      float4_ a1hi = *(const float4_*)(ap + 36);
      half8 a0, a1;
#pragma unroll
      for (int u = 0; u < 4; ++u) {
        a0[u]     = (_Float16)a0lo[u];
        a0[u + 4] = (_Float16)a0hi[u];
        a1[u]     = (_Float16)a1lo[u];
        a1[u + 4] = (_Float16)a1hi[u];
      }
      const _Float16* bp = w1m + (size_t)n * (MMID * I1);
      half8 bf0 = *(const half8*)(bp);
      half8 bf1 = *(const half8*)(bp + 32);
      float4_ acc = {0.f, 0.f, 0.f, 0.f};
      acc = __builtin_amdgcn_mfma_f32_16x16x32_f16(a0, bf0, acc, 0, 0, 0);
      acc = __builtin_amdgcn_mfma_f32_16x16x32_f16(a1, bf1, acc, 0, 0, 0);
      acc4[nn] = acc;
    }
    // D[row=quad*4+r (b)][col=row (m_local)]; pack 4 consecutive n -> b64.
#pragma unroll
    for (int r = 0; r < 4; ++r) {
      const int b    = quad * 4 + r;
      const int swz  = ((b + row) & 7) << 4;
      const int byte = (b * 16 + row) * 256 + ((n0 * 2) ^ swz);
      half4_ v = { (_Float16)acc4[0][r], (_Float16)acc4[1][r],
                   (_Float16)acc4[2][r], (_Float16)acc4[3][r] };
      *(half4_*)((char*)tl + byte) = v;
    }
  }
  __syncthreads();

  // ---------------- phase 2: out = t @ conn2 ----------------
#pragma unroll
  for (int mi = 0; mi < 4; ++mi) {
    const int ml = wave * 4 + mi;      // m_local 0..15
    const int mg = m0 + ml;            // global m 0..63
    // A-frags: lane row = b, k = n = ks*32 + quad*8 + u (swizzle matches writes)
    half8 af[4];
#pragma unroll
    for (int ks = 0; ks < 4; ++ks) {
      const int swz  = ((row + ml) & 7) << 4;
      const int byte = (row * 16 + ml) * 256 + ((ks * 64 + quad * 16) ^ swz);
      af[ks] = *(const half8*)((const char*)tl + byte);
    }
    const _Float16* bbase =
        conn2T + (size_t)mg * (OOUT * N1) + (size_t)row * N1 + kk;
    float4_ acc[8];
#pragma unroll
    for (int ot = 0; ot < 8; ++ot) acc[ot] = (float4_){0.f, 0.f, 0.f, 0.f};
#pragma unroll
    for (int ks = 0; ks < 4; ++ks) {
#pragma unroll
      for (int ot = 0; ot < 8; ++ot) {
        half8 bf = *(const half8*)(bbase + (size_t)(ot * 16) * N1 + ks * 32);
        acc[ot] = __builtin_amdgcn_mfma_f32_16x16x32_f16(af[ks], bf, acc[ot], 0, 0, 0);
      }
    }
    // Epilogue: 16 lanes x 4B = 64B contiguous per (ot, r); L2 merges rows.
    float* obase = out + (size_t)b0 * LDX + (size_t)mg * OOUT + row;
#pragma unroll
    for (int ot = 0; ot < 8; ++ot) {
#pragma unroll
      for (int r = 0; r < 4; ++r) {
        obase[(size_t)(quad * 4 + r) * LDX + ot * 16] = acc[ot][r];
      }
    }
  }
}

// ---------------------------------------------------------------------------
extern "C" void kernel_launch(void* const* d_in, const int* in_sizes, int n_in,
                              void* d_out, int out_size, void* d_ws, size_t ws_size,
                              hipStream_t stream) {
  (void)in_sizes; (void)n_in; (void)out_size; (void)ws_size;
  const float* x  = (const float*)d_in[0];
  const float* c1 = (const float*)d_in[1];
  const float* c2 = (const float*)d_in[2];
  float* out = (float*)d_out;

  // Workspace (fp16 elems): conn1T 524288, conn2T 1048576 (t2 eliminated)
  _Float16* conn1T = (_Float16*)d_ws;
  _Float16* conn2T = conn1T + (size_t)N1 * MMID * I1;

  prep_kernel<<<64, 256, 0, stream>>>(c1, c2, conn1T, conn2T);
  fused_kernel<<<dim3(BATCH / 16 * 4), 256, 0, stream>>>(x, conn1T, conn2T, out);
}

// Round 2
// 364.880 us; speedup vs baseline: 1.0159x; 1.0159x over previous
//
#include <hip/hip_runtime.h>

// Problem constants
#define BATCH     4096
#define N1        128     // n blocks (stage-1 block index, stage-2 K dim)
#define I1        64      // inputs per block 1 (stage-1 K dim)
#define MMID      64      // outputs per block 1 == n blocks 2
#define OOUT      128     // outputs per block 2
#define LDX       8192    // x row length
#define CSP       3.0f

typedef _Float16 half8  __attribute__((ext_vector_type(8)));
typedef _Float16 half4_ __attribute__((ext_vector_type(4)));
typedef float    float4_ __attribute__((ext_vector_type(4)));

// ---------------------------------------------------------------------------
// Kernel 1: softmax prep (unchanged).
//  conn1T[n][m][i] = softmax_i(3*c1[n][i][m])   (fp16, i contiguous)
//  conn2T[m][o][n] = softmax_n(3*c2[m][n][o])   (fp16, n contiguous)
// ---------------------------------------------------------------------------
__global__ __launch_bounds__(256) void prep_kernel(
    const float* __restrict__ c1, const float* __restrict__ c2,
    _Float16* __restrict__ conn1T, _Float16* __restrict__ conn2T) {
  int gid = blockIdx.x * 256 + threadIdx.x;
  if (gid < N1 * MMID) {
    const float* p = c1 + (size_t)(gid >> 6) * (I1 * MMID) + (gid & 63);
    float mx = -1e30f;
    for (int i = 0; i < I1; ++i) mx = fmaxf(mx, p[i * MMID]);
    mx *= CSP;
    float s = 0.f;
    for (int i = 0; i < I1; ++i) s += __expf(p[i * MMID] * CSP - mx);
    float inv = 1.0f / s;
    _Float16* dst = conn1T + (size_t)gid * I1;
    for (int i = 0; i < I1; ++i)
      dst[i] = (_Float16)(__expf(p[i * MMID] * CSP - mx) * inv);
  } else {
    int g = gid - N1 * MMID;
    if (g < MMID * OOUT) {
      const float* p = c2 + (size_t)(g >> 7) * (N1 * OOUT) + (g & 127);
      float mx = -1e30f;
      for (int i = 0; i < N1; ++i) mx = fmaxf(mx, p[i * OOUT]);
      mx *= CSP;
      float s = 0.f;
      for (int i = 0; i < N1; ++i) s += __expf(p[i * OOUT] * CSP - mx);
      float inv = 1.0f / s;
      _Float16* dst = conn2T + (size_t)g * N1;
      for (int i = 0; i < N1; ++i)
        dst[i] = (_Float16)(__expf(p[i * OOUT] * CSP - mx) * inv);
    }
  }
}

// ---------------------------------------------------------------------------
// Kernel 2: FUSED stage1+stage2. Block = (b-tile 16, m-quarter 16), 8 WAVES.
// Phase 1: wave w computes t[b][m0..m0+16][n] for n in [w*16, w*16+16) via
//   MFMA (A = x fp32->fp16, B = conn1T) and writes the 16x16x128 fp16 t-tile
//   to LDS (64 KB), n-position XOR-swizzled by ((b+m)&7)<<4 bytes.
// Phase 2 (one barrier): wave w owns 2 m's; A-frags are swizzled ds_read_b128
//   from LDS, B = conn2T (L2-hot), 32 K=32 MFMAs per m, fp32 stores to out.
// t never touches HBM. Grid id swizzle pins the 4 m-quarter siblings of a
// b-tile to one XCD so the x re-reads are L2 hits.
// Occupancy: 64 KB LDS -> 2 blocks/CU x 8 waves = 16 waves/CU (4/SIMD);
// __launch_bounds__(512,4) caps VGPR at 128 (prev build: 116, fits).
// ---------------------------------------------------------------------------
__global__ __launch_bounds__(512, 4) void fused_kernel(
    const float* __restrict__ x, const _Float16* __restrict__ conn1T,
    const _Float16* __restrict__ conn2T, float* __restrict__ out) {
  __shared__ _Float16 tl[16 * 16 * 128];   // 64 KB: [b][m][n] + XOR swizzle

  const int bid  = blockIdx.x;
  const int bt   = ((bid >> 5) << 3) | (bid & 7);  // b-tile 0..255
  const int q    = (bid >> 3) & 3;                 // m-quarter 0..3
  const int b0   = bt * 16;
  const int m0   = q * 16;
  const int tid  = threadIdx.x;
  const int lane = tid & 63;
  const int wave = tid >> 6;            // 0..7
  const int row  = lane & 15;
  const int quad = lane >> 4;
  const int kk   = quad * 8;

  // ---------------- phase 1: t-tile into LDS ----------------
  const float* xrow = x + (size_t)(b0 + row) * LDX;
  const _Float16* w1m = conn1T + (size_t)(m0 + row) * I1 + kk;

#pragma unroll 2
  for (int g = 0; g < 4; ++g) {
    const int n0 = wave * 16 + g * 4;
    float4_ acc4[4];
#pragma unroll
    for (int nn = 0; nn < 4; ++nn) {
      const int n = n0 + nn;
      const float* ap = xrow + n * I1 + kk;
      float4_ a0lo = *(const float4_*)(ap);
      float4_ a0hi = *(const float4_*)(ap + 4);
      float4_ a1lo = *(const float4_*)(ap + 32);
      float4_ a1hi = *(const float4_*)(ap + 36);
      half8 a0, a1;
#pragma unroll
      for (int u = 0; u < 4; ++u) {
        a0[u]     = (_Float16)a0lo[u];
        a0[u + 4] = (_Float16)a0hi[u];
        a1[u]     = (_Float16)a1lo[u];
        a1[u + 4] = (_Float16)a1hi[u];
      }
      const _Float16* bp = w1m + (size_t)n * (MMID * I1);
      half8 bf0 = *(const half8*)(bp);
      half8 bf1 = *(const half8*)(bp + 32);
      float4_ acc = {0.f, 0.f, 0.f, 0.f};
      acc = __builtin_amdgcn_mfma_f32_16x16x32_f16(a0, bf0, acc, 0, 0, 0);
      acc = __builtin_amdgcn_mfma_f32_16x16x32_f16(a1, bf1, acc, 0, 0, 0);
      acc4[nn] = acc;
    }
    // D[row=quad*4+r (b)][col=row (m_local)]; pack 4 consecutive n -> b64.
#pragma unroll
    for (int r = 0; r < 4; ++r) {
      const int b    = quad * 4 + r;
      const int swz  = ((b + row) & 7) << 4;
      const int byte = (b * 16 + row) * 256 + ((n0 * 2) ^ swz);
      half4_ v = { (_Float16)acc4[0][r], (_Float16)acc4[1][r],
                   (_Float16)acc4[2][r], (_Float16)acc4[3][r] };
      *(half4_*)((char*)tl + byte) = v;
    }
  }
  __syncthreads();

  // ---------------- phase 2: out = t @ conn2 ----------------
#pragma unroll
  for (int mi = 0; mi < 2; ++mi) {
    const int ml = wave * 2 + mi;      // m_local 0..15
    const int mg = m0 + ml;            // global m 0..63
    // A-frags: lane row = b, k = n = ks*32 + quad*8 + u (swizzle matches writes)
    half8 af[4];
#pragma unroll
    for (int ks = 0; ks < 4; ++ks) {
      const int swz  = ((row + ml) & 7) << 4;
      const int byte = (row * 16 + ml) * 256 + ((ks * 64 + quad * 16) ^ swz);
      af[ks] = *(const half8*)((const char*)tl + byte);
    }
    const _Float16* bbase =
        conn2T + (size_t)mg * (OOUT * N1) + (size_t)row * N1 + kk;
    float4_ acc[8];
#pragma unroll
    for (int ot = 0; ot < 8; ++ot) acc[ot] = (float4_){0.f, 0.f, 0.f, 0.f};
#pragma unroll
    for (int ks = 0; ks < 4; ++ks) {
#pragma unroll
      for (int ot = 0; ot < 8; ++ot) {
        half8 bf = *(const half8*)(bbase + (size_t)(ot * 16) * N1 + ks * 32);
        acc[ot] = __builtin_amdgcn_mfma_f32_16x16x32_f16(af[ks], bf, acc[ot], 0, 0, 0);
      }
    }
    // Epilogue: 16 lanes x 4B = 64B contiguous per (ot, r); L2 merges rows.
    float* obase = out + (size_t)b0 * LDX + (size_t)mg * OOUT + row;
#pragma unroll
    for (int ot = 0; ot < 8; ++ot) {
#pragma unroll
      for (int r = 0; r < 4; ++r) {
        obase[(size_t)(quad * 4 + r) * LDX + ot * 16] = acc[ot][r];
      }
    }
  }
}

// ---------------------------------------------------------------------------
extern "C" void kernel_launch(void* const* d_in, const int* in_sizes, int n_in,
                              void* d_out, int out_size, void* d_ws, size_t ws_size,
                              hipStream_t stream) {
  (void)in_sizes; (void)n_in; (void)out_size; (void)ws_size;
  const float* x  = (const float*)d_in[0];
  const float* c1 = (const float*)d_in[1];
  const float* c2 = (const float*)d_in[2];
  float* out = (float*)d_out;

  // Workspace (fp16 elems): conn1T 524288, conn2T 1048576 (t2 eliminated)
  _Float16* conn1T = (_Float16*)d_ws;
  _Float16* conn2T = conn1T + (size_t)N1 * MMID * I1;

  prep_kernel<<<64, 256, 0, stream>>>(c1, c2, conn1T, conn2T);
  fused_kernel<<<dim3(BATCH / 16 * 4), 512, 0, stream>>>(x, conn1T, conn2T, out);
}